// Round 2
// baseline (348.340 us; speedup 1.0000x reference)
//
#include <hip/hip_runtime.h>
#include <hip/hip_bf16.h>

// Problem constants (from reference setup_inputs)
#define C1    256      // feature channels
#define C2    128      // encoder channels
#define COUT  256      // output channels
#define MM    4096     // feature length
#define NN    16384    // encoder / output length
#define BB    8        // batch
#define BN_EPS 1e-5f
#define SLOPE 0.2f

typedef float  f32x4  __attribute__((ext_vector_type(4)));
typedef __bf16 bf16x8 __attribute__((ext_vector_type(8)));
typedef short  s16x8  __attribute__((ext_vector_type(8)));

static __device__ __forceinline__ unsigned short f2bf(float f) {
    // round-to-nearest-even f32 -> bf16 bits (inputs are finite)
    unsigned int u = __builtin_bit_cast(unsigned int, f);
    unsigned int r = (u + 0x7FFFu + ((u >> 16) & 1u)) >> 16;
    return (unsigned short)r;
}

static __device__ __forceinline__ bf16x8 ld_frag(const unsigned short* p) {
    s16x8 v = *reinterpret_cast<const s16x8*>(p);
    union { s16x8 s; bf16x8 b; } cvt;
    cvt.s = v;
    return cvt.b;
}

// ---------------------------------------------------------------------------
// K1: Zt[b][m][o] = sum_c feature[b,c,m] * W[C2+c, o]     (bf16 MFMA)
// tile: 64 m x 64 o, K=256 staged in two passes of 128
// ---------------------------------------------------------------------------
__global__ __launch_bounds__(256) void k1_zt(const float* __restrict__ feature,
                                             const float* __restrict__ W,
                                             float* __restrict__ Zt) {
    const int mt = blockIdx.x;   // 0..63
    const int ot = blockIdx.y;   // 0..3
    const int b  = blockIdx.z;   // 0..7
    const int mb = mt * 64, ob = ot * 64;
    const int tid = threadIdx.x;

    __shared__ unsigned short sA[64 * 136];  // featT[m][k] (k slice of 128, pad 8)
    __shared__ unsigned short sB[64 * 136];  // Wt[o][k]

    const int wid = tid >> 6, lane = tid & 63;
    const int r = lane & 15, g = lane >> 4;
    const int wm = (wid >> 1) * 32, wo = (wid & 1) * 32;

    f32x4 acc[2][2];
#pragma unroll
    for (int i = 0; i < 2; i++)
#pragma unroll
        for (int j = 0; j < 2; j++) acc[i][j] = (f32x4){0.f, 0.f, 0.f, 0.f};

    for (int kp = 0; kp < 2; kp++) {
        const int k0 = kp * 128;
        // stage featT: global reads coalesced along m
        for (int p = tid; p < 64 * 64; p += 256) {
            int m = p & 63, k = (p >> 6) * 2;
            float f0 = feature[(size_t)(b * C1 + k0 + k) * MM + mb + m];
            float f1 = feature[(size_t)(b * C1 + k0 + k + 1) * MM + mb + m];
            ushort2 u; u.x = f2bf(f0); u.y = f2bf(f1);
            *reinterpret_cast<ushort2*>(&sA[m * 136 + k]) = u;
        }
        // stage Wt[o][k] from W[C2+k][ob+o]
        for (int p = tid; p < 64 * 64; p += 256) {
            int o = p & 63, k = (p >> 6) * 2;
            float f0 = W[(C2 + k0 + k) * COUT + ob + o];
            float f1 = W[(C2 + k0 + k + 1) * COUT + ob + o];
            ushort2 u; u.x = f2bf(f0); u.y = f2bf(f1);
            *reinterpret_cast<ushort2*>(&sB[o * 136 + k]) = u;
        }
        __syncthreads();

#pragma unroll
        for (int ks = 0; ks < 4; ks++) {
            const int kb = ks * 32 + g * 8;
            bf16x8 a0 = ld_frag(&sA[(wm +  0 + r) * 136 + kb]);
            bf16x8 a1 = ld_frag(&sA[(wm + 16 + r) * 136 + kb]);
            bf16x8 b0 = ld_frag(&sB[(wo +  0 + r) * 136 + kb]);
            bf16x8 b1 = ld_frag(&sB[(wo + 16 + r) * 136 + kb]);
            acc[0][0] = __builtin_amdgcn_mfma_f32_16x16x32_bf16(a0, b0, acc[0][0], 0, 0, 0);
            acc[0][1] = __builtin_amdgcn_mfma_f32_16x16x32_bf16(a0, b1, acc[0][1], 0, 0, 0);
            acc[1][0] = __builtin_amdgcn_mfma_f32_16x16x32_bf16(a1, b0, acc[1][0], 0, 0, 0);
            acc[1][1] = __builtin_amdgcn_mfma_f32_16x16x32_bf16(a1, b1, acc[1][1], 0, 0, 0);
        }
        __syncthreads();
    }

    // D layout: row = 4*g + i, col = r   [measured m89]
#pragma unroll
    for (int fm = 0; fm < 2; fm++)
#pragma unroll
        for (int fo = 0; fo < 2; fo++)
#pragma unroll
            for (int i = 0; i < 4; i++) {
                int m = mb + wm + fm * 16 + g * 4 + i;
                int o = ob + wo + fo * 16 + r;
                Zt[((size_t)b * MM + m) * COUT + o] = acc[fm][fo][i];
            }
}

// ---------------------------------------------------------------------------
// K2: y[b][o][n] = bias[o] + Zt[b][idx[b,n]][o] + sum_k enc[b,k,n]*W[k,o]
// tile: 64 o x 128 n, K=128; writes raw y to d_out, accumulates per-(b,o) stats
// ---------------------------------------------------------------------------
__global__ __launch_bounds__(256) void k2_main(const float* __restrict__ enc,
                                               const float* __restrict__ W,
                                               const float* __restrict__ bias,
                                               const int*   __restrict__ idx,
                                               const float* __restrict__ Zt,
                                               float* __restrict__ y,
                                               float* __restrict__ sums,    // [BB][COUT]
                                               float* __restrict__ sumsq) { // [BB][COUT]
    const int nt = blockIdx.x;   // 0..127
    const int ot = blockIdx.y;   // 0..3
    const int b  = blockIdx.z;   // 0..7
    const int nb = nt * 128, ob = ot * 64;
    const int tid = threadIdx.x;

    __shared__ unsigned short sB[128 * 136]; // encT[n][k]; reused as Zl[128][68] f32
    __shared__ unsigned short sA[64 * 136];  // Wt[o][k]
    __shared__ int   sIdx[128];
    __shared__ float lsum[64], lsq[64];

    if (tid < 128) sIdx[tid] = idx[b * NN + nb + tid];
    if (tid < 64) { lsum[tid] = 0.f; lsq[tid] = 0.f; }

    for (int p = tid; p < 128 * 64; p += 256) {
        int n = p & 127, k = (p >> 7) * 2;
        float f0 = enc[(size_t)(b * C2 + k) * NN + nb + n];
        float f1 = enc[(size_t)(b * C2 + k + 1) * NN + nb + n];
        ushort2 u; u.x = f2bf(f0); u.y = f2bf(f1);
        *reinterpret_cast<ushort2*>(&sB[n * 136 + k]) = u;
    }
    for (int p = tid; p < 64 * 64; p += 256) {
        int o = p & 63, k = (p >> 6) * 2;
        float f0 = W[k * COUT + ob + o];
        float f1 = W[(k + 1) * COUT + ob + o];
        ushort2 u; u.x = f2bf(f0); u.y = f2bf(f1);
        *reinterpret_cast<ushort2*>(&sA[o * 136 + k]) = u;
    }
    __syncthreads();

    const int wid = tid >> 6, lane = tid & 63;
    const int r = lane & 15, g = lane >> 4;
    const int wo = (wid >> 1) * 32;  // wave's o offset (0/32)
    const int wn = (wid & 1) * 64;   // wave's n offset (0/64)

    f32x4 acc[2][4];
#pragma unroll
    for (int i = 0; i < 2; i++)
#pragma unroll
        for (int j = 0; j < 4; j++) acc[i][j] = (f32x4){0.f, 0.f, 0.f, 0.f};

#pragma unroll
    for (int ks = 0; ks < 4; ks++) {
        const int kb = ks * 32 + g * 8;
        bf16x8 a0 = ld_frag(&sA[(wo +  0 + r) * 136 + kb]);
        bf16x8 a1 = ld_frag(&sA[(wo + 16 + r) * 136 + kb]);
        bf16x8 bf[4];
#pragma unroll
        for (int fn = 0; fn < 4; fn++)
            bf[fn] = ld_frag(&sB[(wn + fn * 16 + r) * 136 + kb]);
#pragma unroll
        for (int fn = 0; fn < 4; fn++) {
            acc[0][fn] = __builtin_amdgcn_mfma_f32_16x16x32_bf16(a0, bf[fn], acc[0][fn], 0, 0, 0);
            acc[1][fn] = __builtin_amdgcn_mfma_f32_16x16x32_bf16(a1, bf[fn], acc[1][fn], 0, 0, 0);
        }
    }
    __syncthreads();  // all waves done reading encT before overwrite

    // stage gathered Zt rows into LDS (coalesced 256B global rows), Zl[128][68]
    float* Zl = reinterpret_cast<float*>(sB);
    {
        const int lr = tid & 15;
        for (int row = tid >> 4; row < 128; row += 16) {
            const float4 v = reinterpret_cast<const float4*>(
                &Zt[((size_t)b * MM + sIdx[row]) * COUT + ob])[lr];
            reinterpret_cast<float4*>(&Zl[row * 68])[lr] = v;
        }
    }
    __syncthreads();

    float bi[2][4];
#pragma unroll
    for (int fo = 0; fo < 2; fo++)
#pragma unroll
        for (int i = 0; i < 4; i++)
            bi[fo][i] = bias[ob + wo + fo * 16 + g * 4 + i];

    float s_[2][4] = {{0.f,0.f,0.f,0.f},{0.f,0.f,0.f,0.f}};
    float q_[2][4] = {{0.f,0.f,0.f,0.f},{0.f,0.f,0.f,0.f}};
#pragma unroll
    for (int fo = 0; fo < 2; fo++)
#pragma unroll
        for (int fn = 0; fn < 4; fn++) {
            const int n_loc = wn + fn * 16 + r;
            // float4 (ds_read_b128): 64 lanes' 16B runs tile all 32 banks
            // exactly 8x (minimum) with the 68-float row pad -> conflict-free
            const f32x4 z = *reinterpret_cast<const f32x4*>(
                &Zl[n_loc * 68 + wo + fo * 16 + g * 4]);
#pragma unroll
            for (int i = 0; i < 4; i++) {
                int o_loc = wo + fo * 16 + g * 4 + i;
                float v = acc[fo][fn][i] + z[i] + bi[fo][i];
                y[(size_t)(b * COUT + ob + o_loc) * NN + nb + n_loc] = v;
                s_[fo][i] += v;
                q_[fo][i] += v * v;
            }
        }

    // reduce across the 16 col-lanes (o_loc constant under xor of low 4 bits)
#pragma unroll
    for (int d = 1; d < 16; d <<= 1)
#pragma unroll
        for (int fo = 0; fo < 2; fo++)
#pragma unroll
            for (int i = 0; i < 4; i++) {
                s_[fo][i] += __shfl_xor(s_[fo][i], d);
                q_[fo][i] += __shfl_xor(q_[fo][i], d);
            }
    if (r == 0) {
#pragma unroll
        for (int fo = 0; fo < 2; fo++)
#pragma unroll
            for (int i = 0; i < 4; i++) {
                int o_loc = wo + fo * 16 + g * 4 + i;
                atomicAdd(&lsum[o_loc], s_[fo][i]);
                atomicAdd(&lsq[o_loc],  q_[fo][i]);
            }
    }
    __syncthreads();
    if (tid < 64) {
        atomicAdd(&sums [b * COUT + ob + tid], lsum[tid]);
        atomicAdd(&sumsq[b * COUT + ob + tid], lsq[tid]);
    }
}

// ---------------------------------------------------------------------------
// K3: fold per-(b,o) partial sums into per-channel affine a,c
// ---------------------------------------------------------------------------
__global__ void k3_stats(const float* __restrict__ sums,
                         const float* __restrict__ sumsq,
                         const float* __restrict__ gamma,
                         const float* __restrict__ beta,
                         float* __restrict__ ac) {  // [0..255]=a, [256..511]=c
    const int o = threadIdx.x;
    float s = 0.f, q = 0.f;
#pragma unroll
    for (int b = 0; b < BB; b++) {
        s += sums [b * COUT + o];
        q += sumsq[b * COUT + o];
    }
    const float inv_cnt = 1.0f / ((float)BB * (float)NN);
    float mean = s * inv_cnt;
    float var  = q * inv_cnt - mean * mean;
    float a = gamma[o] * rsqrtf(var + BN_EPS);
    float c = beta[o] - mean * a;
    ac[o] = a;
    ac[COUT + o] = c;
}

// ---------------------------------------------------------------------------
// K4: in-place normalize + LeakyReLU, float4 grid-stride
// ---------------------------------------------------------------------------
__global__ __launch_bounds__(256) void k4_norm(float* __restrict__ y,
                                               const float* __restrict__ ac) {
    const size_t total4 = (size_t)BB * COUT * NN / 4;
    const size_t stride = (size_t)gridDim.x * 256;
    for (size_t i = (size_t)blockIdx.x * 256 + threadIdx.x; i < total4; i += stride) {
        float4 v = reinterpret_cast<float4*>(y)[i];
        int o = (int)((i * 4) >> 14) & 255;  // (elem / NN) % COUT, NN = 2^14
        float a = ac[o], c = ac[COUT + o];
        float t0 = a * v.x + c; v.x = t0 > 0.f ? t0 : SLOPE * t0;
        float t1 = a * v.y + c; v.y = t1 > 0.f ? t1 : SLOPE * t1;
        float t2 = a * v.z + c; v.z = t2 > 0.f ? t2 : SLOPE * t2;
        float t3 = a * v.w + c; v.w = t3 > 0.f ? t3 : SLOPE * t3;
        reinterpret_cast<float4*>(y)[i] = v;
    }
}

extern "C" void kernel_launch(void* const* d_in, const int* in_sizes, int n_in,
                              void* d_out, int out_size, void* d_ws, size_t ws_size,
                              hipStream_t stream) {
    const float* feature = (const float*)d_in[0];   // [8,256,4096]
    const float* enc     = (const float*)d_in[1];   // [8,128,16384]
    const int*   idx     = (const int*)  d_in[2];   // [8,16384]
    const float* W       = (const float*)d_in[3];   // [384,256]
    const float* bias    = (const float*)d_in[4];   // [256]
    const float* gamma   = (const float*)d_in[5];   // [256]
    const float* beta    = (const float*)d_in[6];   // [256]
    float* out = (float*)d_out;                     // [8,256,16384]

    float* sums  = (float*)d_ws;                    // [8][256]
    float* sumsq = sums + BB * COUT;                // [8][256]
    float* ac    = sumsq + BB * COUT;               // [512]
    float* Zt    = ac + 2 * COUT;                   // [8][4096][256] = 32 MiB

    hipMemsetAsync(sums, 0, 2 * BB * COUT * sizeof(float), stream);

    k1_zt  <<<dim3(MM / 64, COUT / 64, BB), 256, 0, stream>>>(feature, W, Zt);
    k2_main<<<dim3(NN / 128, COUT / 64, BB), 256, 0, stream>>>(enc, W, bias, idx, Zt,
                                                               out, sums, sumsq);
    k3_stats<<<1, COUT, 0, stream>>>(sums, sumsq, gamma, beta, ac);
    k4_norm<<<2048, 256, 0, stream>>>(out, ac);
}

// Round 3
// 325.338 us; speedup vs baseline: 1.0707x; 1.0707x over previous
//
#include <hip/hip_runtime.h>
#include <hip/hip_bf16.h>

// Problem constants (from reference setup_inputs)
#define C1    256      // feature channels
#define C2    128      // encoder channels
#define COUT  256      // output channels
#define MM    4096     // feature length
#define NN    16384    // encoder / output length
#define BB    8        // batch
#define BN_EPS 1e-5f
#define SLOPE 0.2f

typedef float  f32x4  __attribute__((ext_vector_type(4)));
typedef __bf16 bf16x8 __attribute__((ext_vector_type(8)));
typedef unsigned short u16x8 __attribute__((ext_vector_type(8)));

#define GLOBAL_AS __attribute__((address_space(1)))
#define LDS_AS    __attribute__((address_space(3)))

static __device__ __forceinline__ unsigned short f2bf(float f) {
    // round-to-nearest-even f32 -> bf16 bits (inputs are finite)
    unsigned int u = __builtin_bit_cast(unsigned int, f);
    unsigned int r = (u + 0x7FFFu + ((u >> 16) & 1u)) >> 16;
    return (unsigned short)r;
}

static __device__ __forceinline__ bf16x8 ld_frag(const unsigned short* p) {
    union { u16x8 s; bf16x8 b; } cvt;
    cvt.s = *reinterpret_cast<const u16x8*>(p);
    return cvt.b;
}

// ---------------------------------------------------------------------------
// K1: Zt[b][m][o] = sum_c feature[b,c,m] * W[C2+c, o]     (bf16 MFMA)
// tile: 64 m x 64 o, K=256 staged in two passes of 128
// staging: 16B-per-lane writes -> bank-uniform (8 words/bank = minimum)
// ---------------------------------------------------------------------------
__global__ __launch_bounds__(256, 4) void k1_zt(const float* __restrict__ feature,
                                                const float* __restrict__ W,
                                                float* __restrict__ Zt) {
    const int mt = blockIdx.x;   // 0..63
    const int ot = blockIdx.y;   // 0..3
    const int b  = blockIdx.z;   // 0..7
    const int mb = mt * 64, ob = ot * 64;
    const int tid = threadIdx.x;

    __shared__ unsigned short sA[64 * 136];  // featT[m][k] (k slice of 128, pad 8)
    __shared__ unsigned short sB[64 * 136];  // Wt[o][k]

    const int wid = tid >> 6, lane = tid & 63;
    const int r = lane & 15, g = lane >> 4;
    const int wm = (wid >> 1) * 32, wo = (wid & 1) * 32;

    f32x4 acc[2][2];
#pragma unroll
    for (int i = 0; i < 2; i++)
#pragma unroll
        for (int j = 0; j < 2; j++) acc[i][j] = (f32x4){0.f, 0.f, 0.f, 0.f};

    for (int kp = 0; kp < 2; kp++) {
        const int k0 = kp * 128;
        // stage featT[m][k]: lane packs 8 k-values, one 16B LDS write
        for (int p = tid; p < 64 * 16; p += 256) {
            int m = p & 63, k = (p >> 6) << 3;
            u16x8 u;
#pragma unroll
            for (int j = 0; j < 8; j++)
                u[j] = f2bf(feature[(size_t)(b * C1 + k0 + k + j) * MM + mb + m]);
            *reinterpret_cast<u16x8*>(&sA[m * 136 + k]) = u;
        }
        // stage Wt[o][k] from W[C2+k][ob+o]
        for (int p = tid; p < 64 * 16; p += 256) {
            int o = p & 63, k = (p >> 6) << 3;
            u16x8 u;
#pragma unroll
            for (int j = 0; j < 8; j++)
                u[j] = f2bf(W[(C2 + k0 + k + j) * COUT + ob + o]);
            *reinterpret_cast<u16x8*>(&sB[o * 136 + k]) = u;
        }
        __syncthreads();

#pragma unroll
        for (int ks = 0; ks < 4; ks++) {
            const int kb = ks * 32 + g * 8;
            bf16x8 a0 = ld_frag(&sA[(wm +  0 + r) * 136 + kb]);
            bf16x8 a1 = ld_frag(&sA[(wm + 16 + r) * 136 + kb]);
            bf16x8 b0 = ld_frag(&sB[(wo +  0 + r) * 136 + kb]);
            bf16x8 b1 = ld_frag(&sB[(wo + 16 + r) * 136 + kb]);
            acc[0][0] = __builtin_amdgcn_mfma_f32_16x16x32_bf16(a0, b0, acc[0][0], 0, 0, 0);
            acc[0][1] = __builtin_amdgcn_mfma_f32_16x16x32_bf16(a0, b1, acc[0][1], 0, 0, 0);
            acc[1][0] = __builtin_amdgcn_mfma_f32_16x16x32_bf16(a1, b0, acc[1][0], 0, 0, 0);
            acc[1][1] = __builtin_amdgcn_mfma_f32_16x16x32_bf16(a1, b1, acc[1][1], 0, 0, 0);
        }
        __syncthreads();
    }

    // D layout: row = 4*g + i, col = r   [measured m89]
#pragma unroll
    for (int fm = 0; fm < 2; fm++)
#pragma unroll
        for (int fo = 0; fo < 2; fo++)
#pragma unroll
            for (int i = 0; i < 4; i++) {
                int m = mb + wm + fm * 16 + g * 4 + i;
                int o = ob + wo + fo * 16 + r;
                Zt[((size_t)b * MM + m) * COUT + o] = acc[fm][fo][i];
            }
}

// ---------------------------------------------------------------------------
// K2: y[b][o][n] = bias[o] + Zt[b][idx[b,n]][o] + sum_k enc[b,k,n]*W[k,o]
// tile: 64 o x 128 n, K=128. W frags in registers (L2-resident), enc in LDS,
// Zt gather via global_load_lds (linear dest + XOR-swizzled source + swizzled
// read). LDS ~35KB -> 4 blocks/CU.
// ---------------------------------------------------------------------------
__global__ __launch_bounds__(256, 4) void k2_main(const float* __restrict__ enc,
                                                  const float* __restrict__ W,
                                                  const float* __restrict__ bias,
                                                  const int*   __restrict__ idx,
                                                  const float* __restrict__ Zt,
                                                  float* __restrict__ y,
                                                  float* __restrict__ sums,    // [BB][COUT]
                                                  float* __restrict__ sumsq) { // [BB][COUT]
    const int nt = blockIdx.x;   // 0..127
    const int ot = blockIdx.y;   // 0..3
    const int b  = blockIdx.z;   // 0..7
    const int nb = nt * 128, ob = ot * 64;
    const int tid = threadIdx.x;

    __shared__ unsigned short sB[128 * 136]; // encT[n][k]; aliased as Zl[128][64] f32
    __shared__ float lsum[64], lsq[64];

    if (tid < 64) { lsum[tid] = 0.f; lsq[tid] = 0.f; }

    const int wid = tid >> 6, lane = tid & 63;
    const int r = lane & 15, g = lane >> 4;
    const int wo = (wid >> 1) * 32;  // wave's o offset (0/32)
    const int wn = (wid & 1) * 64;   // wave's n offset (0/64)

    // W fragments -> registers: wf[ks][fr][j] = W[ks*32+g*8+j][ob+wo+fr*16+r]
    bf16x8 wf[4][2];
#pragma unroll
    for (int ks = 0; ks < 4; ks++)
#pragma unroll
        for (int fr = 0; fr < 2; fr++) {
            u16x8 tmp;
#pragma unroll
            for (int j = 0; j < 8; j++)
                tmp[j] = f2bf(W[(ks * 32 + g * 8 + j) * COUT + ob + wo + fr * 16 + r]);
            union { u16x8 u; bf16x8 b; } cv; cv.u = tmp;
            wf[ks][fr] = cv.b;
        }

    // stage encT[n][k]: 16B per lane, bank-uniform
    for (int p = tid; p < 128 * 16; p += 256) {
        int n = p & 127, k = (p >> 7) << 3;
        u16x8 u;
#pragma unroll
        for (int j = 0; j < 8; j++)
            u[j] = f2bf(enc[(size_t)(b * C2 + k + j) * NN + nb + n]);
        *reinterpret_cast<u16x8*>(&sB[n * 136 + k]) = u;
    }
    __syncthreads();

    f32x4 acc[2][4];
#pragma unroll
    for (int i = 0; i < 2; i++)
#pragma unroll
        for (int j = 0; j < 4; j++) acc[i][j] = (f32x4){0.f, 0.f, 0.f, 0.f};

#pragma unroll
    for (int ks = 0; ks < 4; ks++) {
        const int kb = ks * 32 + g * 8;
        bf16x8 bfr[4];
#pragma unroll
        for (int fn = 0; fn < 4; fn++)
            bfr[fn] = ld_frag(&sB[(wn + fn * 16 + r) * 136 + kb]);
#pragma unroll
        for (int fn = 0; fn < 4; fn++) {
            acc[0][fn] = __builtin_amdgcn_mfma_f32_16x16x32_bf16(wf[ks][0], bfr[fn], acc[0][fn], 0, 0, 0);
            acc[1][fn] = __builtin_amdgcn_mfma_f32_16x16x32_bf16(wf[ks][1], bfr[fn], acc[1][fn], 0, 0, 0);
        }
    }
    __syncthreads();  // all waves done reading encT before overwrite

    // gather Zt rows -> Zl[128][64] via global_load_lds (linear LDS dest,
    // XOR col-swizzle applied on the per-lane GLOBAL source; rule #21)
    float* Zl = reinterpret_cast<float*>(sB);
    {
        const int lrow = lane >> 4;      // 0..3
        const int lcol = lane & 15;      // dest granule
        const int* idxb = idx + b * NN + nb;
#pragma unroll
        for (int it = 0; it < 8; it++) {
            const int wrow = wid * 32 + it * 4;
            const int row  = wrow + lrow;
            const int zi   = idxb[row];
            const float* src = &Zt[((size_t)b * MM + zi) * COUT + ob +
                                   ((lcol ^ (row & 15)) << 2)];
            __builtin_amdgcn_global_load_lds(
                (const GLOBAL_AS unsigned int*)src,
                (LDS_AS unsigned int*)(&Zl[wrow * 64]), 16, 0, 0);
        }
    }
    __syncthreads();

    float bi[2][4];
#pragma unroll
    for (int fo = 0; fo < 2; fo++)
#pragma unroll
        for (int i = 0; i < 4; i++)
            bi[fo][i] = bias[ob + wo + fo * 16 + g * 4 + i];

    float s_[2][4] = {{0.f,0.f,0.f,0.f},{0.f,0.f,0.f,0.f}};
    float q_[2][4] = {{0.f,0.f,0.f,0.f},{0.f,0.f,0.f,0.f}};
#pragma unroll
    for (int fo = 0; fo < 2; fo++)
#pragma unroll
        for (int fn = 0; fn < 4; fn++) {
            const int n_loc = wn + fn * 16 + r;
            const int o4 = (wo >> 2) + fo * 4 + g;          // logical granule
            // swizzled read: physical granule = o4 ^ (n_loc & 15) = o4 ^ r
            const f32x4 z = *reinterpret_cast<const f32x4*>(
                &Zl[n_loc * 64 + ((o4 ^ r) << 2)]);
#pragma unroll
            for (int i = 0; i < 4; i++) {
                int o_loc = wo + fo * 16 + g * 4 + i;
                float v = acc[fo][fn][i] + z[i] + bi[fo][i];
                y[(size_t)(b * COUT + ob + o_loc) * NN + nb + n_loc] = v;
                s_[fo][i] += v;
                q_[fo][i] += v * v;
            }
        }

    // reduce across the 16 col-lanes (o_loc constant under xor of low 4 bits)
#pragma unroll
    for (int d = 1; d < 16; d <<= 1)
#pragma unroll
        for (int fo = 0; fo < 2; fo++)
#pragma unroll
            for (int i = 0; i < 4; i++) {
                s_[fo][i] += __shfl_xor(s_[fo][i], d);
                q_[fo][i] += __shfl_xor(q_[fo][i], d);
            }
    if (r == 0) {
#pragma unroll
        for (int fo = 0; fo < 2; fo++)
#pragma unroll
            for (int i = 0; i < 4; i++) {
                int o_loc = wo + fo * 16 + g * 4 + i;
                atomicAdd(&lsum[o_loc], s_[fo][i]);
                atomicAdd(&lsq[o_loc],  q_[fo][i]);
            }
    }
    __syncthreads();
    if (tid < 64) {
        atomicAdd(&sums [b * COUT + ob + tid], lsum[tid]);
        atomicAdd(&sumsq[b * COUT + ob + tid], lsq[tid]);
    }
}

// ---------------------------------------------------------------------------
// K3: fold per-(b,o) partial sums into per-channel affine a,c
// ---------------------------------------------------------------------------
__global__ void k3_stats(const float* __restrict__ sums,
                         const float* __restrict__ sumsq,
                         const float* __restrict__ gamma,
                         const float* __restrict__ beta,
                         float* __restrict__ ac) {  // [0..255]=a, [256..511]=c
    const int o = threadIdx.x;
    float s = 0.f, q = 0.f;
#pragma unroll
    for (int b = 0; b < BB; b++) {
        s += sums [b * COUT + o];
        q += sumsq[b * COUT + o];
    }
    const float inv_cnt = 1.0f / ((float)BB * (float)NN);
    float mean = s * inv_cnt;
    float var  = q * inv_cnt - mean * mean;
    float a = gamma[o] * rsqrtf(var + BN_EPS);
    float c = beta[o] - mean * a;
    ac[o] = a;
    ac[COUT + o] = c;
}

// ---------------------------------------------------------------------------
// K4: in-place normalize + LeakyReLU, float4 grid-stride
// ---------------------------------------------------------------------------
__global__ __launch_bounds__(256) void k4_norm(float* __restrict__ y,
                                               const float* __restrict__ ac) {
    const size_t total4 = (size_t)BB * COUT * NN / 4;
    const size_t stride = (size_t)gridDim.x * 256;
    for (size_t i = (size_t)blockIdx.x * 256 + threadIdx.x; i < total4; i += stride) {
        float4 v = reinterpret_cast<float4*>(y)[i];
        int o = (int)((i * 4) >> 14) & 255;  // (elem / NN) % COUT, NN = 2^14
        float a = ac[o], c = ac[COUT + o];
        float t0 = a * v.x + c; v.x = t0 > 0.f ? t0 : SLOPE * t0;
        float t1 = a * v.y + c; v.y = t1 > 0.f ? t1 : SLOPE * t1;
        float t2 = a * v.z + c; v.z = t2 > 0.f ? t2 : SLOPE * t2;
        float t3 = a * v.w + c; v.w = t3 > 0.f ? t3 : SLOPE * t3;
        reinterpret_cast<float4*>(y)[i] = v;
    }
}

extern "C" void kernel_launch(void* const* d_in, const int* in_sizes, int n_in,
                              void* d_out, int out_size, void* d_ws, size_t ws_size,
                              hipStream_t stream) {
    const float* feature = (const float*)d_in[0];   // [8,256,4096]
    const float* enc     = (const float*)d_in[1];   // [8,128,16384]
    const int*   idx     = (const int*)  d_in[2];   // [8,16384]
    const float* W       = (const float*)d_in[3];   // [384,256]
    const float* bias    = (const float*)d_in[4];   // [256]
    const float* gamma   = (const float*)d_in[5];   // [256]
    const float* beta    = (const float*)d_in[6];   // [256]
    float* out = (float*)d_out;                     // [8,256,16384]

    float* sums  = (float*)d_ws;                    // [8][256]
    float* sumsq = sums + BB * COUT;                // [8][256]
    float* ac    = sumsq + BB * COUT;               // [512]
    float* Zt    = ac + 2 * COUT;                   // [8][4096][256] = 32 MiB

    hipMemsetAsync(sums, 0, 2 * BB * COUT * sizeof(float), stream);

    k1_zt  <<<dim3(MM / 64, COUT / 64, BB), 256, 0, stream>>>(feature, W, Zt);
    k2_main<<<dim3(NN / 128, COUT / 64, BB), 256, 0, stream>>>(enc, W, bias, idx, Zt,
                                                               out, sums, sumsq);
    k3_stats<<<1, COUT, 0, stream>>>(sums, sumsq, gamma, beta, ac);
    k4_norm<<<2048, 256, 0, stream>>>(out, ac);
}